// Round 6
// baseline (265.524 us; speedup 1.0000x reference)
//
#include <hip/hip_runtime.h>
#include <hip/hip_bf16.h>

#define N_ 2048
#define D_ 128
#define B_ 8
#define BKC 64                                   // j-extent per block
#define IGROUP 256                               // i-extent per block
#define ITERS (IGROUP / 64)                      // 4 i-tiles of 64 rows
#define NBLOCKS (B_ * (N_ / BKC) * (N_ / IGROUP))  // 8*32*8 = 2048

typedef __attribute__((ext_vector_type(8))) short short8;
typedef __attribute__((ext_vector_type(4))) short short4v;
typedef __attribute__((ext_vector_type(4))) float f32x4;

__device__ __forceinline__ unsigned short f2bf(float x) {
  unsigned int u = __builtin_bit_cast(unsigned int, x);
  u += 0x7fffu + ((u >> 16) & 1u);   // RNE; finite inputs
  return (unsigned short)(u >> 16);
}

__device__ __forceinline__ short4v pack4(float4 a) {
  short4v o;
  o[0] = (short)f2bf(a.x); o[1] = (short)f2bf(a.y);
  o[2] = (short)f2bf(a.z); o[3] = (short)f2bf(a.w);
  return o;
}

// Build VT[b][128][2048] = bf16(emb^T), hsq[b][2048] fp32. Block = 64 nodes.
__global__ __launch_bounds__(256) void prep_kernel(
    const float* __restrict__ emb, unsigned short* __restrict__ vt,
    float* __restrict__ hsq) {
  __shared__ float semb[64 * 132];
  __shared__ float shsq[64];
  const int t = threadIdx.x;
  const int bb = blockIdx.x >> 5;
  const int j0 = (blockIdx.x & 31) << 6;
  const float* ebase = emb + ((size_t)(bb * N_ + j0)) * D_;
#pragma unroll
  for (int it = 0; it < 8; ++it) {
    int fidx = it * 1024 + t * 4;
    int j = fidx >> 7, d = fidx & 127;
    const float4 v = *(const float4*)(ebase + (size_t)j * D_ + d);
    *(float4*)&semb[j * 132 + d] = v;
  }
  __syncthreads();
  {
    int j = t >> 2, q = t & 3;
    const float* row = &semb[j * 132 + q * 32];
    float p = 0.f;
#pragma unroll
    for (int x = 0; x < 32; ++x) p += row[x] * row[x];
    p += __shfl_down(p, 2);
    p += __shfl_down(p, 1);
    if (q == 0) { shsq[j] = p; hsq[bb * N_ + j0 + j] = p; }
  }
  __syncthreads();
  unsigned short* vbase = vt + (size_t)bb * D_ * N_ + j0;
#pragma unroll
  for (int it = 0; it < 4; ++it) {
    int idx = it * 256 + t;
    int d = idx >> 3, jg = idx & 7;
    short8 o;
#pragma unroll
    for (int x = 0; x < 8; ++x)
      o[x] = (short)f2bf(semb[(jg * 8 + x) * 132 + d]);
    *(short8*)&vbase[(size_t)d * N_ + jg * 8] = o;
  }
}

// Loop-over-i block: V-frags register-cached (loaded once, L2-hot, coalesced),
// A loaded coalesced (16 rows x 64B full lines) and redistributed to MFMA
// fragment ownership via a wave-local swizzled LDS transpose (no barriers
// anywhere in the loop; DS ops are in-order per wave).
__global__ __launch_bounds__(256, 3) void gemm_kernel(
    const float* __restrict__ adj, const float* __restrict__ emb,
    const float* __restrict__ hsq, const unsigned short* __restrict__ vt,
    float* __restrict__ partials) {
  __shared__ unsigned short lsw[4 * 1024];   // 2 KB per wave
  __shared__ float red[4];

  const int t = threadIdx.x;
  const int lane = t & 63, wave = t >> 6;
  const int lhalf = lane & 15, quad = lane >> 4;
  const int bid = blockIdx.x;
  const int b = bid & 7;                     // XCD-affine batch
  const int rem = bid >> 3;
  const int jk = (rem & 31) * BKC;           // 32 j-chunks of 64
  const int i0g = (rem >> 5) * IGROUP;       // 8 i-groups of 256

  const unsigned short* vtb = vt + (size_t)b * D_ * N_;
  const float* embb = emb + (size_t)b * N_ * D_;
  const float* hsqb = hsq + b * N_;
  const float* abase = adj + ((size_t)b << 22);

  // --- V-fragments: 16 x short8 = 64 VGPRs, once per block, coalesced L2 reads
  short8 Vf[8][2];
#pragma unroll
  for (int nt = 0; nt < 8; ++nt)
#pragma unroll
    for (int s = 0; s < 2; ++s)
      Vf[nt][s] = *(const short8*)(vtb + (size_t)(nt * 16 + lhalf) * N_ +
                                   jk + s * 32 + quad * 8);

  // --- per-lane cooperative A mapping: row = lane>>2 (16 rows), seg = lane&3
  const int crow = lane >> 2, seg = lane & 3;
  float4 hc[4];
#pragma unroll
  for (int s = 0; s < 4; ++s)
    hc[s] = *(const float4*)(hsqb + jk + seg * 4 + s * 16);

  unsigned short* lw = lsw + wave * 1024;
  const float* aptr = abase + (size_t)(i0g + wave * 16 + crow) * N_ + jk + seg * 4;

  float4 A[4];
#pragma unroll
  for (int s = 0; s < 4; ++s) A[s] = *(const float4*)(aptr + s * 16);
  float hr = hsqb[i0g + wave * 16 + crow];

  float p1 = 0.f, p2 = 0.f, pc = 0.f;

#pragma unroll 1
  for (int itr = 0; itr < ITERS; ++itr) {
    // exact fp32 hsq terms in cooperative layout
    float rs = 0.f;
#pragma unroll
    for (int s = 0; s < 4; ++s) {
      rs += A[s].x + A[s].y + A[s].z + A[s].w;
      p2 += A[s].x * hc[s].x + A[s].y * hc[s].y + A[s].z * hc[s].z + A[s].w * hc[s].w;
    }
    p1 += rs * hr;

    // pack + wave-local LDS transpose (XOR-swizzled 16B units, no barrier)
#pragma unroll
    for (int s = 0; s < 4; ++s) {
      int unit = (seg >> 1) + s * 2;                 // 16B unit within row
      int idx = crow * 64 + ((unit ^ (crow & 7)) << 3) + ((seg & 1) << 2);
      *(short4v*)&lw[idx] = pack4(A[s]);
    }
    asm volatile("s_waitcnt lgkmcnt(0)" ::: "memory");
    short8 fa0 = *(const short8*)&lw[lhalf * 64 + ((quad ^ (lhalf & 7)) << 3)];
    short8 fa1 = *(const short8*)&lw[lhalf * 64 + (((quad + 4) ^ (lhalf & 7)) << 3)];

    // MFMA: 16 per iter, acc zeroed per i-tile
    f32x4 acc[8] = {};
#pragma unroll
    for (int nt = 0; nt < 8; ++nt) {
      acc[nt] = __builtin_amdgcn_mfma_f32_16x16x32_bf16(fa0, Vf[nt][0], acc[nt], 0, 0, 0);
      acc[nt] = __builtin_amdgcn_mfma_f32_16x16x32_bf16(fa1, Vf[nt][1], acc[nt], 0, 0, 0);
    }

    // epilogue: C/D col(d)=lane&15, row(i)=quad*4+reg; coalesced 64B emb reads
#pragma unroll
    for (int r = 0; r < 4; ++r) {
      const float* erow = embb + (size_t)(i0g + itr * 64 + wave * 16 + quad * 4 + r) * D_;
#pragma unroll
      for (int nt = 0; nt < 8; ++nt)
        pc += acc[nt][r] * erow[nt * 16 + lhalf];
    }

    // A prefetch LAST (FIFO vmcnt: next iter waits only on these, drains nothing newer)
    if (itr + 1 < ITERS) {
      const float* apn = aptr + (size_t)(itr + 1) * 64 * N_;
#pragma unroll
      for (int s = 0; s < 4; ++s) A[s] = *(const float4*)(apn + s * 16);
      hr = hsqb[i0g + (itr + 1) * 64 + wave * 16 + crow];
    }
  }

  float part = p1 + p2 - 2.0f * pc;
#pragma unroll
  for (int off = 32; off > 0; off >>= 1) part += __shfl_down(part, off);
  if (lane == 0) red[wave] = part;
  __syncthreads();
  if (t == 0) partials[bid] = red[0] + red[1] + red[2] + red[3];
}

__global__ void finish_kernel(const float* __restrict__ partials,
                              float* __restrict__ out) {
  __shared__ double sred[4];
  const int t = threadIdx.x;
  double s = 0.0;
#pragma unroll
  for (int it = 0; it < NBLOCKS / 256; ++it)
    s += (double)partials[it * 256 + t];
#pragma unroll
  for (int off = 32; off > 0; off >>= 1) s += __shfl_down(s, off);
  if ((t & 63) == 0) sred[t >> 6] = s;
  __syncthreads();
  if (t == 0)
    out[0] = (float)((sred[0] + sred[1] + sred[2] + sred[3]) /
                     (double)((size_t)B_ * N_));
}

extern "C" void kernel_launch(void* const* d_in, const int* in_sizes, int n_in,
                              void* d_out, int out_size, void* d_ws, size_t ws_size,
                              hipStream_t stream) {
  const float* adj = (const float*)d_in[0];
  const float* emb = (const float*)d_in[1];
  float* hsq = (float*)d_ws;                                   // 64 KiB
  unsigned short* vt = (unsigned short*)((char*)d_ws + 65536); // 4 MiB
  float* partials = (float*)((char*)d_ws + 65536 + (size_t)B_ * D_ * N_ * 2);

  prep_kernel<<<B_ * (N_ / 64), 256, 0, stream>>>(emb, vt, hsq);
  gemm_kernel<<<NBLOCKS, 256, 0, stream>>>(adj, emb, hsq, vt, partials);
  finish_kernel<<<1, 256, 0, stream>>>(partials, (float*)d_out);
}